// Round 9
// baseline (621.313 us; speedup 1.0000x reference)
//
#include <hip/hip_runtime.h>
#include <hip/hip_bf16.h>

typedef __attribute__((ext_vector_type(8))) short short8;
typedef __attribute__((ext_vector_type(16))) float floatx16;
typedef __attribute__((ext_vector_type(4))) float floatx4;

#define AS1 __attribute__((address_space(1)))
#define AS3 __attribute__((address_space(3)))

constexpr int MM = 65536;   // batch
constexpr int KK = 512;     // inner dim
constexpr int NN = 512;     // out dim per layer

#define GK 32
#define LDT 40   // logits kernel LDS row stride (shorts)

// round-to-nearest-even fp32 -> bf16 (bit-level, finite inputs)
__device__ __forceinline__ unsigned short bf16_rn(float v) {
  unsigned u = __float_as_uint(v);
  return (unsigned short)((u + 0x7FFFu + ((u >> 16) & 1u)) >> 16);
}
__device__ __forceinline__ float bf16_to_f32(unsigned short h) {
  return __uint_as_float((unsigned)h << 16);
}

// src fp32 -> (hi, lo) bf16 arrays. n4 = element count / 4. (weights only now)
__global__ __launch_bounds__(256) void split_kernel(
    const float* __restrict__ src, unsigned short* __restrict__ h,
    unsigned short* __restrict__ l, int n4) {
  int i = blockIdx.x * 256 + threadIdx.x;
  if (i >= n4) return;
  float4 v = ((const float4*)src)[i];
  ushort4 hv, lv;
  hv.x = bf16_rn(v.x); lv.x = bf16_rn(v.x - bf16_to_f32(hv.x));
  hv.y = bf16_rn(v.y); lv.y = bf16_rn(v.y - bf16_to_f32(hv.y));
  hv.z = bf16_rn(v.z); lv.z = bf16_rn(v.z - bf16_to_f32(hv.z));
  hv.w = bf16_rn(v.w); lv.w = bf16_rn(v.w - bf16_to_f32(hv.w));
  ((ushort4*)h)[i] = hv;
  ((ushort4*)l)[i] = lv;
}

// ---------------------------------------------------------------------------
// GEMM layers 2,3 (A already split): R9 4-phase interleave, unchanged.
// LDS layout (shorts): addr = buf*32768 + arr*8192 + row*32; arr 0=Ah 1=Al
// 2=Bh 3=Bl. Swizzle: phys chunk p of row r holds logical p ^ ((r>>1)&3).
// ---------------------------------------------------------------------------
template<bool RELU>
__global__ __launch_bounds__(512, 1) void gemm_mfma(
    const unsigned short* __restrict__ Ah, const unsigned short* __restrict__ Al,
    const unsigned short* __restrict__ Wh, const unsigned short* __restrict__ Wl,
    const float* __restrict__ bias,
    unsigned short* __restrict__ Ch, unsigned short* __restrict__ Cl) {
  __shared__ __align__(16) unsigned short smem[65536];   // 128 KB
  const int tid = threadIdx.x;
  const int lane = tid & 63;
  const int wid = tid >> 6;          // 0..7
  const int wr = wid >> 2;           // 0..1 : 128-row half
  const int wc = wid & 3;            // 0..3 : 64-col strip
  const int nwg = gridDim.x;         // 512
  const int hw  = blockIdx.x;
  const int logical = (hw & 7) * (nwg >> 3) + (hw >> 3);
  const int bm = logical >> 1, bn = logical & 1;
  const size_t Abase = (size_t)bm * 256 * KK;
  const size_t Bbase = (size_t)bn * 256 * KK;

  const int sarr  = wid >> 1;
  const int rbase = (wid & 1) * 128;
  const unsigned short* gsrc = (sarr == 0) ? Ah : (sarr == 1) ? Al
                             : (sarr == 2) ? Wh : Wl;
  const size_t tb = (sarr < 2) ? Abase : Bbase;
  const int rowl = lane >> 2;
  const int gch  = (lane & 3) ^ ((lane >> 3) & 3);
  const unsigned short* gbase = gsrc + tb + (size_t)(rbase + rowl) * KK + gch * 8;
  unsigned short* ldst = smem + sarr * 8192 + rbase * 32;

  auto stage2 = [&](int buf, int kk, int p) {
#pragma unroll
    for (int j = p * 2; j < p * 2 + 2; ++j) {
      __builtin_amdgcn_global_load_lds(
          (const AS1 unsigned int*)(gbase + (size_t)(j * 16) * KK + kk),
          (AS3 unsigned int*)(ldst + buf * 32768 + j * 16 * 32),
          16, 0, 0);
    }
  };

  floatx16 acc[4][2];
#pragma unroll
  for (int i = 0; i < 4; ++i)
#pragma unroll
    for (int j = 0; j < 2; ++j)
#pragma unroll
      for (int r = 0; r < 16; ++r) acc[i][j][r] = 0.f;

#pragma unroll
  for (int p = 0; p < 4; ++p) stage2(0, 0, p);

  const int swz = (lane >> 1) & 3;
#pragma unroll
  for (int t = 0; t < 16; ++t) {
    const int cur = t & 1;
    const unsigned short* base = smem + cur * 32768;
    short8 fbh[2], fbl[2];
#pragma unroll
    for (int p = 0; p < 4; ++p) {
      const int ks = p >> 1, h = p & 1;
      const int ch = ks * 2 + (lane >> 5);
      const int sw = (ch ^ swz) * 8;
      short8 fah[2], fal[2];

      if (p == 0) {
        if (t < 15) {
          stage2(cur ^ 1, (t + 1) * GK, 0);
          asm volatile("s_waitcnt vmcnt(2)" ::: "memory");
        } else {
          asm volatile("s_waitcnt vmcnt(0)" ::: "memory");
        }
        __builtin_amdgcn_s_barrier();
        __builtin_amdgcn_sched_barrier(0);
      }

#pragma unroll
      for (int q = 0; q < 2; ++q) {
        int row = wr * 128 + (h * 2 + q) * 32 + (lane & 31);
        fah[q] = *(const short8*)(base + row * 32 + sw);
        fal[q] = *(const short8*)(base + 8192 + row * 32 + sw);
      }
      if (h == 0) {
#pragma unroll
        for (int si = 0; si < 2; ++si) {
          int col = wc * 64 + si * 32 + (lane & 31);
          fbh[si] = *(const short8*)(base + 16384 + col * 32 + sw);
          fbl[si] = *(const short8*)(base + 24576 + col * 32 + sw);
        }
      }

      if (p > 0) {
        if (t < 15) stage2(cur ^ 1, (t + 1) * GK, p);
        __builtin_amdgcn_sched_barrier(0);
        __builtin_amdgcn_s_barrier();
        __builtin_amdgcn_sched_barrier(0);
      }

      __builtin_amdgcn_s_setprio(1);
#pragma unroll
      for (int q = 0; q < 2; ++q)
#pragma unroll
        for (int si = 0; si < 2; ++si) {
          const int ri = h * 2 + q;
          acc[ri][si] = __builtin_amdgcn_mfma_f32_32x32x16_bf16(fah[q], fbh[si], acc[ri][si], 0, 0, 0);
          acc[ri][si] = __builtin_amdgcn_mfma_f32_32x32x16_bf16(fah[q], fbl[si], acc[ri][si], 0, 0, 0);
          acc[ri][si] = __builtin_amdgcn_mfma_f32_32x32x16_bf16(fal[q], fbh[si], acc[ri][si], 0, 0, 0);
        }
      __builtin_amdgcn_s_setprio(0);
      __builtin_amdgcn_sched_barrier(0);
      __builtin_amdgcn_s_barrier();
    }
  }

  // chunked coalesced epilogue (R8-verified)
  float bv[2];
#pragma unroll
  for (int si = 0; si < 2; ++si)
    bv[si] = bias[bn * 256 + wc * 64 + si * 32 + (lane & 31)];

  unsigned* lds32 = (unsigned*)smem;
#pragma unroll
  for (int ri = 0; ri < 4; ++ri) {
    __syncthreads();
#pragma unroll
    for (int si = 0; si < 2; ++si) {
      int lcol = wc * 64 + si * 32 + (lane & 31);
#pragma unroll
      for (int r = 0; r < 16; ++r) {
        int frow = (r & 3) + 8 * (r >> 2) + 4 * (lane >> 5);
        float v = acc[ri][si][r] + bv[si];
        if (RELU) v = fmaxf(v, 0.f);
        unsigned short h = bf16_rn(v);
        unsigned short lo = bf16_rn(v - bf16_to_f32(h));
        lds32[(wr * 32 + frow) * 256 + lcol] = (unsigned)h | ((unsigned)lo << 16);
      }
    }
    __syncthreads();
#pragma unroll
    for (int p = 0; p < 8; ++p) {
      int c = tid + p * 512;
      int lrow = c >> 6;
      int cc = (c & 63) * 4;
      uint4 d = *(const uint4*)&lds32[lrow * 256 + cc];
      ushort4 hv, lv;
      hv.x = (unsigned short)(d.x); lv.x = (unsigned short)(d.x >> 16);
      hv.y = (unsigned short)(d.y); lv.y = (unsigned short)(d.y >> 16);
      hv.z = (unsigned short)(d.z); lv.z = (unsigned short)(d.z >> 16);
      hv.w = (unsigned short)(d.w); lv.w = (unsigned short)(d.w >> 16);
      int grow = bm * 256 + (lrow >> 5) * 128 + ri * 32 + (lrow & 31);
      size_t gi = (size_t)grow * NN + bn * 256 + cc;
      *(ushort4*)&Ch[gi] = hv;
      *(ushort4*)&Cl[gi] = lv;
    }
  }
}

// ---------------------------------------------------------------------------
// GEMM layer 1: A = x (fp32) split on the fly. R11 schedule fix vs R10:
// (a) p0 issues loadA THEN stageB; counted vmcnt(8) retires only B(t) --
//     B gets a full tile of latency slack (was vmcnt(0) mid-tile drain);
// (b) convert+write split: p2-end vmcnt(6) -> av[0..1], p3-end vmcnt(4) ->
//     av[2..3]; lgkmcnt(0) + publish barrier. Ledger invariant: 4 B
//     outstanding entering every p0. MFMA order identical to R10.
// ---------------------------------------------------------------------------
__global__ __launch_bounds__(512, 1) void gemm_x(
    const float* __restrict__ X,
    const unsigned short* __restrict__ Wh, const unsigned short* __restrict__ Wl,
    const float* __restrict__ bias,
    unsigned short* __restrict__ Ch, unsigned short* __restrict__ Cl) {
  __shared__ __align__(16) unsigned short smem[65536];   // 128 KB, same layout
  const int tid = threadIdx.x;
  const int lane = tid & 63;
  const int wid = tid >> 6;
  const int wr = wid >> 2;
  const int wc = wid & 3;
  const int nwg = gridDim.x;
  const int hw  = blockIdx.x;
  const int logical = (hw & 7) * (nwg >> 3) + (hw >> 3);
  const int bm = logical >> 1, bn = logical & 1;

  // B staging: wave w -> array (w>>2): 0=Wh, 1=Wl; rows (w&3)*64 .. +64
  const int barr = wid >> 2;
  const int brb  = (wid & 3) * 64;
  const int rowl = lane >> 2;
  const int gch  = (lane & 3) ^ ((lane >> 3) & 3);
  const unsigned short* gbB = (barr ? Wl : Wh) + (size_t)bn * 256 * KK
                            + (size_t)(brb + rowl) * KK + gch * 8;
  unsigned short* ldB = smem + (2 + barr) * 8192 + brb * 32;

  auto stageB = [&](int buf, int kk) {
#pragma unroll
    for (int j = 0; j < 4; ++j) {
      __builtin_amdgcn_global_load_lds(
          (const AS1 unsigned int*)(gbB + (size_t)(j * 16) * KK + kk),
          (AS3 unsigned int*)(ldB + buf * 32768 + j * 16 * 32),
          16, 0, 0);
    }
  };

  // A f32 loads: wave w -> rows w*32 .. +32
  const int arow = lane >> 3;
  const int akc  = lane & 7;
  const float* gx = X + ((size_t)(bm * 256 + wid * 32) + arow) * KK + akc * 4;
  auto loadA = [&](int kk, float4* av) {
#pragma unroll
    for (int j = 0; j < 4; ++j)
      av[j] = *(const float4*)(gx + (size_t)(j * 8) * KK + kk);
  };
  const int apc = ((akc >> 1) ^ ((arow >> 1) & 3));
  const int aoff = (wid * 32 + arow) * 32 + apc * 8 + (akc & 1) * 4;
  auto writeA1 = [&](int buf, const float4& a, int j) {
    ushort4 hv, lv;
    hv.x = bf16_rn(a.x); lv.x = bf16_rn(a.x - bf16_to_f32(hv.x));
    hv.y = bf16_rn(a.y); lv.y = bf16_rn(a.y - bf16_to_f32(hv.y));
    hv.z = bf16_rn(a.z); lv.z = bf16_rn(a.z - bf16_to_f32(hv.z));
    hv.w = bf16_rn(a.w); lv.w = bf16_rn(a.w - bf16_to_f32(hv.w));
    int o = buf * 32768 + aoff + j * 8 * 32;     // +8 rows per j
    *(ushort4*)(smem + o) = hv;                  // sAh
    *(ushort4*)(smem + 8192 + o) = lv;           // sAl
  };

  floatx16 acc[4][2];
#pragma unroll
  for (int i = 0; i < 4; ++i)
#pragma unroll
    for (int j = 0; j < 2; ++j)
#pragma unroll
      for (int r = 0; r < 16; ++r) acc[i][j][r] = 0.f;

  // prologue: tile 0. A first then B; vmcnt(4) retires A only.
  {
    float4 av0[4];
    loadA(0, av0);
    stageB(0, 0);
    asm volatile("s_waitcnt vmcnt(4)" ::: "memory");
#pragma unroll
    for (int j = 0; j < 4; ++j) writeA1(0, av0[j], j);
    asm volatile("s_waitcnt lgkmcnt(0)" ::: "memory");
    __builtin_amdgcn_s_barrier();
    // outstanding: 4 B(0) -> invariant holds entering t=0 p0
  }

  const int swz = (lane >> 1) & 3;
#pragma unroll
  for (int t = 0; t < 16; ++t) {
    const int cur = t & 1;
    const unsigned short* base = smem + cur * 32768;
    short8 fbh[2], fbl[2];
    float4 av[4];
#pragma unroll
    for (int p = 0; p < 4; ++p) {
      const int ks = p >> 1, h = p & 1;
      const int ch = ks * 2 + (lane >> 5);
      const int sw = (ch ^ swz) * 8;
      short8 fah[2], fal[2];

      if (p == 0) {
        if (t < 15) {
          loadA((t + 1) * GK, av);                 // 4 (oldest of new)
          stageB(cur ^ 1, (t + 1) * GK);           // 4
          asm volatile("s_waitcnt vmcnt(8)" ::: "memory");  // retire B(t)
        } else {
          asm volatile("s_waitcnt vmcnt(0)" ::: "memory");
        }
        __builtin_amdgcn_s_barrier();              // tile t fully visible
        __builtin_amdgcn_sched_barrier(0);
      }

#pragma unroll
      for (int q = 0; q < 2; ++q) {
        int row = wr * 128 + (h * 2 + q) * 32 + (lane & 31);
        fah[q] = *(const short8*)(base + row * 32 + sw);
        fal[q] = *(const short8*)(base + 8192 + row * 32 + sw);
      }
      if (h == 0) {
#pragma unroll
        for (int si = 0; si < 2; ++si) {
          int col = wc * 64 + si * 32 + (lane & 31);
          fbh[si] = *(const short8*)(base + 16384 + col * 32 + sw);
          fbl[si] = *(const short8*)(base + 24576 + col * 32 + sw);
        }
      }

      __builtin_amdgcn_s_setprio(1);
#pragma unroll
      for (int q = 0; q < 2; ++q)
#pragma unroll
        for (int si = 0; si < 2; ++si) {
          const int ri = h * 2 + q;
          acc[ri][si] = __builtin_amdgcn_mfma_f32_32x32x16_bf16(fah[q], fbh[si], acc[ri][si], 0, 0, 0);
          acc[ri][si] = __builtin_amdgcn_mfma_f32_32x32x16_bf16(fah[q], fbl[si], acc[ri][si], 0, 0, 0);
          acc[ri][si] = __builtin_amdgcn_mfma_f32_32x32x16_bf16(fal[q], fbh[si], acc[ri][si], 0, 0, 0);
        }
      __builtin_amdgcn_s_setprio(0);
      __builtin_amdgcn_sched_barrier(0);

      if (p == 2 && t < 15) {
        asm volatile("s_waitcnt vmcnt(6)" ::: "memory");   // av[0..1] landed
        writeA1(cur ^ 1, av[0], 0);
        writeA1(cur ^ 1, av[1], 1);
      }
      if (p == 3) {
        if (t < 15) {
          asm volatile("s_waitcnt vmcnt(4)" ::: "memory"); // av[2..3] landed
          writeA1(cur ^ 1, av[2], 2);
          writeA1(cur ^ 1, av[3], 3);
        }
        asm volatile("s_waitcnt lgkmcnt(0)" ::: "memory"); // A writes visible
      }
      __builtin_amdgcn_s_barrier();                        // end-phase
      __builtin_amdgcn_sched_barrier(0);
    }
  }

  // epilogue: RELU + split, chunked coalesced (identical to gemm_mfma<true>)
  float bv[2];
#pragma unroll
  for (int si = 0; si < 2; ++si)
    bv[si] = bias[bn * 256 + wc * 64 + si * 32 + (lane & 31)];

  unsigned* lds32 = (unsigned*)smem;
#pragma unroll
  for (int ri = 0; ri < 4; ++ri) {
    __syncthreads();
#pragma unroll
    for (int si = 0; si < 2; ++si) {
      int lcol = wc * 64 + si * 32 + (lane & 31);
#pragma unroll
      for (int r = 0; r < 16; ++r) {
        int frow = (r & 3) + 8 * (r >> 2) + 4 * (lane >> 5);
        float v = fmaxf(acc[ri][si][r] + bv[si], 0.f);
        unsigned short h = bf16_rn(v);
        unsigned short lo = bf16_rn(v - bf16_to_f32(h));
        lds32[(wr * 32 + frow) * 256 + lcol] = (unsigned)h | ((unsigned)lo << 16);
      }
    }
    __syncthreads();
#pragma unroll
    for (int p = 0; p < 8; ++p) {
      int c = tid + p * 512;
      int lrow = c >> 6;
      int cc = (c & 63) * 4;
      uint4 d = *(const uint4*)&lds32[lrow * 256 + cc];
      ushort4 hv, lv;
      hv.x = (unsigned short)(d.x); lv.x = (unsigned short)(d.x >> 16);
      hv.y = (unsigned short)(d.y); lv.y = (unsigned short)(d.y >> 16);
      hv.z = (unsigned short)(d.z); lv.z = (unsigned short)(d.z >> 16);
      hv.w = (unsigned short)(d.w); lv.w = (unsigned short)(d.w >> 16);
      int grow = bm * 256 + (lrow >> 5) * 128 + ri * 32 + (lrow & 31);
      size_t gi = (size_t)grow * NN + bn * 256 + cc;
      *(ushort4*)&Ch[gi] = hv;
      *(ushort4*)&Cl[gi] = lv;
    }
  }
}

// ---------------------------------------------------------------------------
// H2+H3: mu = mh @ wgh^T + wgb (1-term), select-write z. R10 structure.
// ---------------------------------------------------------------------------
__global__ __launch_bounds__(512) void gemm_muz(
    const unsigned short* __restrict__ Ahm, const unsigned short* __restrict__ Wh,
    const float* __restrict__ bias, const float* __restrict__ y_in,
    float* __restrict__ z_out) {
  __shared__ __align__(16) unsigned short smem[32768];   // 64 KB
  const int tid = threadIdx.x;
  const int lane = tid & 63;
  const int wid = tid >> 6;
  const int wr = wid >> 2;
  const int wc = wid & 3;
  const int bm = blockIdx.x;

  const int sarr = (wid < 4) ? 0 : 1;
  const int rb   = (wid & 3) * 64;
  const unsigned short* gsrc = sarr ? Wh : (Ahm + (size_t)bm * 256 * KK);
  const int rowl = lane >> 2;
  const int gch  = (lane & 3) ^ ((lane >> 3) & 3);
  const unsigned short* gbase = gsrc + (size_t)(rb + rowl) * KK + gch * 8;
  unsigned short* ldst = smem + sarr * 8192 + rb * 32;

  auto stage1 = [&](int buf, int kk, int j) {
    __builtin_amdgcn_global_load_lds(
        (const AS1 unsigned int*)(gbase + (size_t)(j * 16) * KK + kk),
        (AS3 unsigned int*)(ldst + buf * 16384 + j * 16 * 32),
        16, 0, 0);
  };

  floatx16 acc[4][2];
#pragma unroll
  for (int i = 0; i < 4; ++i)
#pragma unroll
    for (int j = 0; j < 2; ++j)
#pragma unroll
      for (int r = 0; r < 16; ++r) acc[i][j][r] = 0.f;

#pragma unroll
  for (int j = 0; j < 4; ++j) stage1(0, 0, j);

  const int swz = (lane >> 1) & 3;
#pragma unroll
  for (int t = 0; t < 16; ++t) {
    const int cur = t & 1;
    const unsigned short* base = smem + cur * 16384;
    short8 fb[2];
#pragma unroll
    for (int p = 0; p < 4; ++p) {
      const int ks = p >> 1, h = p & 1;
      const int ch = ks * 2 + (lane >> 5);
      const int sw = (ch ^ swz) * 8;
      short8 fa[2];

      if (p == 0) {
        if (t < 15) {
          stage1(cur ^ 1, (t + 1) * GK, 0);
          asm volatile("s_waitcnt vmcnt(1)" ::: "memory");
        } else {
          asm volatile("s_waitcnt vmcnt(0)" ::: "memory");
        }
        __builtin_amdgcn_s_barrier();
        __builtin_amdgcn_sched_barrier(0);
      }

#pragma unroll
      for (int q = 0; q < 2; ++q) {
        int row = wr * 128 + (h * 2 + q) * 32 + (lane & 31);
        fa[q] = *(const short8*)(base + row * 32 + sw);
      }
      if (h == 0) {
#pragma unroll
        for (int si = 0; si < 2; ++si) {
          int col = wc * 64 + si * 32 + (lane & 31);
          fb[si] = *(const short8*)(base + 8192 + col * 32 + sw);
        }
      }

      if (p > 0) {
        if (t < 15) stage1(cur ^ 1, (t + 1) * GK, p);
        __builtin_amdgcn_sched_barrier(0);
        __builtin_amdgcn_s_barrier();
        __builtin_amdgcn_sched_barrier(0);
      }

      __builtin_amdgcn_s_setprio(1);
#pragma unroll
      for (int q = 0; q < 2; ++q)
#pragma unroll
        for (int si = 0; si < 2; ++si)
          acc[h * 2 + q][si] = __builtin_amdgcn_mfma_f32_32x32x16_bf16(fa[q], fb[si], acc[h * 2 + q][si], 0, 0, 0);
      __builtin_amdgcn_s_setprio(0);
      __builtin_amdgcn_sched_barrier(0);
      __builtin_amdgcn_s_barrier();
    }
  }

  // select-epilogue: col in 0..255; class = col>>4, latent e = col&15
  int colv[2]; float bv[2];
#pragma unroll
  for (int si = 0; si < 2; ++si) {
    colv[si] = wc * 64 + si * 32 + (lane & 31);
    bv[si] = bias[colv[si]];
  }
#pragma unroll
  for (int ri = 0; ri < 4; ++ri)
#pragma unroll
    for (int r = 0; r < 16; ++r) {
      int row = bm * 256 + wr * 128 + ri * 32 + (r & 3) + 8 * (r >> 2) + 4 * (lane >> 5);
      int yv = (int)y_in[row];
#pragma unroll
      for (int si = 0; si < 2; ++si) {
        if ((colv[si] >> 4) == yv)
          z_out[(size_t)row * 16 + (colv[si] & 15)] = acc[ri][si][r] + bv[si];
      }
    }
}

// H1: logits[65536,16] = (mh+ml) @ (wch+wcl)^T + bc via 3-term 16x16x32 MFMA,
// then per-row argmax -> y. Unchanged.
__global__ __launch_bounds__(256) void logits_kernel(
    const unsigned short* __restrict__ mh, const unsigned short* __restrict__ ml,
    const unsigned short* __restrict__ wch, const unsigned short* __restrict__ wcl,
    const float* __restrict__ bc, float* __restrict__ y_out) {
  __shared__ unsigned short smh[64][LDT], sml[64][LDT];
  __shared__ float slog[64][17];
  const int tid = threadIdx.x;
  const int lane = tid & 63;
  const int wid = tid >> 6;
  const size_t row0 = (size_t)blockIdx.x * 64;
  const int fr = lane & 15;
  const int fq = lane >> 4;

  floatx4 acc = {0.f, 0.f, 0.f, 0.f};
  const unsigned short* bh = wch + fr * 512 + fq * 8;
  const unsigned short* bl = wcl + fr * 512 + fq * 8;

  for (int k0 = 0; k0 < 512; k0 += 32) {
    {
      int row = tid >> 2, cc = (tid & 3) * 8;
      size_t g = (row0 + row) * 512 + k0 + cc;
      *(short8*)&smh[row][cc] = *(const short8*)(mh + g);
      *(short8*)&sml[row][cc] = *(const short8*)(ml + g);
    }
    __syncthreads();
    short8 ah = *(const short8*)&smh[wid * 16 + fr][fq * 8];
    short8 al = *(const short8*)&sml[wid * 16 + fr][fq * 8];
    short8 fbh = *(const short8*)(bh + k0);
    short8 fbl = *(const short8*)(bl + k0);
    acc = __builtin_amdgcn_mfma_f32_16x16x32_bf16(ah, fbh, acc, 0, 0, 0);
    acc = __builtin_amdgcn_mfma_f32_16x16x32_bf16(ah, fbl, acc, 0, 0, 0);
    acc = __builtin_amdgcn_mfma_f32_16x16x32_bf16(al, fbh, acc, 0, 0, 0);
    __syncthreads();
  }
#pragma unroll
  for (int r = 0; r < 4; ++r)
    slog[wid * 16 + fq * 4 + r][fr] = acc[r] + bc[fr];
  __syncthreads();
  if (tid < 64) {
    float best = slog[tid][0];
    int bi = 0;
#pragma unroll
    for (int j = 1; j < 16; ++j) {
      float v = slog[tid][j];
      if (v > best) { best = v; bi = j; }
    }
    y_out[row0 + tid] = (float)bi;
  }
}

// prep: Wg[16,32,512] mu-rows -> wgh[256,512] bf16; wgb[col]=bg[col/16,col%16]
__global__ __launch_bounds__(256) void prep_wg(
    const float* __restrict__ Wg, const float* __restrict__ bg,
    unsigned short* __restrict__ wgh, float* __restrict__ wgb) {
  int gid = blockIdx.x * 256 + threadIdx.x;
  if (gid >= 32768) return;
  int r = gid >> 7;
  int c4 = (gid & 127) * 4;
  int k = r >> 4, e = r & 15;
  float4 v = *(const float4*)(Wg + ((size_t)k * 32 + e) * 512 + c4);
  ushort4 h;
  h.x = bf16_rn(v.x); h.y = bf16_rn(v.y); h.z = bf16_rn(v.z); h.w = bf16_rn(v.w);
  *(ushort4*)(wgh + (size_t)r * 512 + c4) = h;
  if (c4 == 0) wgb[r] = bg[k * 32 + e];
}

extern "C" void kernel_launch(void* const* d_in, const int* in_sizes, int n_in,
                              void* d_out, int out_size, void* d_ws, size_t ws_size,
                              hipStream_t stream) {
  const float* x  = (const float*)d_in[0];
  const float* W0 = (const float*)d_in[1];
  const float* b0 = (const float*)d_in[2];
  const float* W1 = (const float*)d_in[3];
  const float* b1 = (const float*)d_in[4];
  const float* W2 = (const float*)d_in[5];
  const float* b2 = (const float*)d_in[6];
  const float* Wc = (const float*)d_in[7];
  const float* bc = (const float*)d_in[8];
  const float* Wg = (const float*)d_in[9];
  const float* bg = (const float*)d_in[10];

  const size_t NEL = (size_t)MM * KK;
  unsigned short* Ah = (unsigned short*)d_ws;           // 64 MiB each
  unsigned short* Al = Ah + NEL;
  unsigned short* Bh = Al + NEL;
  unsigned short* Bl = Bh + NEL;
  // After GEMM3 (out: Bh/Bl = m-split), Ah/Al regions are free:
  unsigned short* wch = Al;                             // 16 KB
  unsigned short* wcl = Al + 8192;                      // 16 KB
  unsigned short* wgh = Al + 16384;                     // 256 KB
  float* wgb = (float*)(Al + 16384 + 131072);           // 1 KB

  // W-layer splits staged in d_out (3 MiB < 4.5 MiB); dead once GEMM3 done,
  // then overwritten by z (gemm_muz).
  unsigned short* w0h = (unsigned short*)d_out;
  unsigned short* w0l = w0h + 262144;
  unsigned short* w1h = w0l + 262144;
  unsigned short* w1l = w1h + 262144;
  unsigned short* w2h = w1l + 262144;
  unsigned short* w2l = w2h + 262144;

  float* z_out = (float*)d_out;
  float* y_out = z_out + (size_t)MM * 16;               // at +4 MiB, clear of w-splits

  split_kernel<<<256, 256, 0, stream>>>(W0, w0h, w0l, 65536);
  split_kernel<<<256, 256, 0, stream>>>(W1, w1h, w1l, 65536);
  split_kernel<<<256, 256, 0, stream>>>(W2, w2h, w2l, 65536);

  const int ngrid = (MM / 256) * (NN / 256);            // 512, %8==0
  gemm_x<<<ngrid, 512, 0, stream>>>(x, w0h, w0l, b0, Bh, Bl);
  gemm_mfma<true ><<<ngrid, 512, 0, stream>>>(Bh, Bl, w1h, w1l, b1, Ah, Al);
  gemm_mfma<false><<<ngrid, 512, 0, stream>>>(Ah, Al, w2h, w2l, b2, Bh, Bl);

  // head preps (Ah/Al free from here)
  split_kernel<<<8, 256, 0, stream>>>(Wc, wch, wcl, 2048);
  prep_wg<<<128, 256, 0, stream>>>(Wg, bg, wgh, wgb);

  logits_kernel<<<MM / 64, 256, 0, stream>>>(Bh, Bl, wch, wcl, bc, y_out);
  gemm_muz<<<MM / 256, 512, 0, stream>>>(Bh, wgh, wgb, y_out, z_out);
}